// Round 9
// baseline (10334.789 us; speedup 1.0000x reference)
//
#include <hip/hip_runtime.h>
#include <hip/hip_bf16.h>

// Problem dims
#define TT    2048
#define DD    1024
#define HH    2048
#define TAGS_ 1024
#define G4    8192   // 4*H

typedef float f32x4 __attribute__((ext_vector_type(4)));
typedef __bf16 bf16x8 __attribute__((ext_vector_type(8)));
typedef _Float16 f16x2 __attribute__((ext_vector_type(2)));
typedef _Float16 f16x4 __attribute__((ext_vector_type(4)));
typedef unsigned u32x2 __attribute__((ext_vector_type(2)));

__device__ __forceinline__ unsigned short f2bf(float f) {
    unsigned u = __float_as_uint(f);
    unsigned r = (u + 0x7fffu + ((u >> 16) & 1u)) >> 16;
    return (unsigned short)r;
}

__device__ __forceinline__ f16x2 u2h(unsigned u) {
    return __builtin_bit_cast(f16x2, u);
}

#if __has_builtin(__builtin_amdgcn_fdot2)
#define FDOT2(a, b, c) __builtin_amdgcn_fdot2((a), (b), (c), false)
#else
__device__ __forceinline__ float FDOT2(f16x2 a, f16x2 b, float c) {
    return fmaf((float)a.x, (float)b.x, fmaf((float)a.y, (float)b.y, c));
}
#endif

// full-wave (64-lane) sum via DPP ladder; result broadcast via readlane 63
__device__ __forceinline__ float dpp_sum64(float x) {
    int t;
    t = __builtin_amdgcn_update_dpp(0, __float_as_int(x), 0x111, 0xf, 0xf, true); // row_shr:1
    x += __int_as_float(t);
    t = __builtin_amdgcn_update_dpp(0, __float_as_int(x), 0x112, 0xf, 0xf, true); // row_shr:2
    x += __int_as_float(t);
    t = __builtin_amdgcn_update_dpp(0, __float_as_int(x), 0x114, 0xf, 0xf, true); // row_shr:4
    x += __int_as_float(t);
    t = __builtin_amdgcn_update_dpp(0, __float_as_int(x), 0x118, 0xf, 0xf, true); // row_shr:8
    x += __int_as_float(t);
    t = __builtin_amdgcn_update_dpp(0, __float_as_int(x), 0x142, 0xa, 0xf, true); // row_bcast:15
    x += __int_as_float(t);
    t = __builtin_amdgcn_update_dpp(0, __float_as_int(x), 0x143, 0xc, 0xf, true); // row_bcast:31
    x += __int_as_float(t);
    return __int_as_float(__builtin_amdgcn_readlane(__float_as_int(x), 63));
}

// ---------------- fp32 -> bf16 convert ----------------
__global__ __launch_bounds__(256) void cvt_bf16_k(const float* __restrict__ in,
                                                  unsigned short* __restrict__ out, int n) {
    int i = (blockIdx.x * 256 + threadIdx.x) * 4;
    if (i < n) {
        float4 v = *(const float4*)(in + i);
        ushort4 o;
        o.x = f2bf(v.x); o.y = f2bf(v.y); o.z = f2bf(v.z); o.w = f2bf(v.w);
        *(ushort4*)(out + i) = o;
    }
}

// ---------------- fp32 -> fp16 convert ----------------
__global__ __launch_bounds__(256) void cvt_f16_k(const float* __restrict__ in,
                                                 _Float16* __restrict__ out, int n) {
    int i = (blockIdx.x * 256 + threadIdx.x) * 4;
    if (i < n) {
        float4 v = *(const float4*)(in + i);
        f16x4 o;
        o.x = (_Float16)v.x; o.y = (_Float16)v.y;
        o.z = (_Float16)v.z; o.w = (_Float16)v.w;
        *(f16x4*)(out + i) = o;
    }
}

// ------------- tagged word (f16 in low16) -> bf16 -------------
__global__ __launch_bounds__(256) void cvt_lo16f_k(const unsigned* __restrict__ in,
                                                   unsigned short* __restrict__ out, int n) {
    int i = (blockIdx.x * 256 + threadIdx.x) * 4;
    if (i < n) {
        uint4 v = *(const uint4*)(in + i);
        ushort4 o;
        o.x = f2bf((float)__builtin_bit_cast(_Float16, (unsigned short)(v.x & 0xffff)));
        o.y = f2bf((float)__builtin_bit_cast(_Float16, (unsigned short)(v.y & 0xffff)));
        o.z = f2bf((float)__builtin_bit_cast(_Float16, (unsigned short)(v.z & 0xffff)));
        o.w = f2bf((float)__builtin_bit_cast(_Float16, (unsigned short)(v.w & 0xffff)));
        *(ushort4*)(out + i) = o;
    }
}

// ---------------- bf16 MFMA GEMM: C[M][N] = A[M][K] * B[N][K]^T + bias ----------------
__global__ __launch_bounds__(256) void gemm_bt_k(const unsigned short* __restrict__ A,
                                                 const unsigned short* __restrict__ B,
                                                 void* __restrict__ Cv,
                                                 const float* __restrict__ bias1,
                                                 const float* __restrict__ bias2,
                                                 int M, int N, int K, int out_f16) {
    const int bn = blockIdx.x, bm = blockIdx.y;
    const int tid = threadIdx.x;
    const int wave = tid >> 6, lane = tid & 63;
    const int wm = (wave >> 1) * 64, wn = (wave & 1) * 64;

    __shared__ unsigned short As[128 * 64];
    __shared__ unsigned short Bs[128 * 64];

    f32x4 acc[4][4] = {};

    for (int k0 = 0; k0 < K; k0 += 64) {
#pragma unroll
        for (int i = 0; i < 4; ++i) {
            int bo = (tid + i * 256) * 16;
            int r = bo >> 7;
            int cb = bo & 127;
            *(uint4*)((char*)As + bo) =
                *(const uint4*)((const char*)(A + (size_t)(bm * 128 + r) * K + k0) + cb);
            *(uint4*)((char*)Bs + bo) =
                *(const uint4*)((const char*)(B + (size_t)(bn * 128 + r) * K + k0) + cb);
        }
        __syncthreads();
#pragma unroll
        for (int kk = 0; kk < 64; kk += 32) {
            int kb = kk + (lane >> 4) * 8;
            bf16x8 af[4], bfr[4];
#pragma unroll
            for (int mi = 0; mi < 4; ++mi)
                af[mi] = *(const bf16x8*)&As[(wm + mi * 16 + (lane & 15)) * 64 + kb];
#pragma unroll
            for (int ni = 0; ni < 4; ++ni)
                bfr[ni] = *(const bf16x8*)&Bs[(wn + ni * 16 + (lane & 15)) * 64 + kb];
#pragma unroll
            for (int mi = 0; mi < 4; ++mi)
#pragma unroll
                for (int ni = 0; ni < 4; ++ni)
                    acc[mi][ni] = __builtin_amdgcn_mfma_f32_16x16x32_bf16(
                        af[mi], bfr[ni], acc[mi][ni], 0, 0, 0);
        }
        __syncthreads();
    }

#pragma unroll
    for (int ni = 0; ni < 4; ++ni) {
        int col = bn * 128 + wn + ni * 16 + (lane & 15);
        float bv = bias1 ? bias1[col] : 0.0f;
        if (bias2) bv += bias2[col];
#pragma unroll
        for (int mi = 0; mi < 4; ++mi) {
            int row = bm * 128 + wm + mi * 16 + (lane >> 4) * 4;
#pragma unroll
            for (int r = 0; r < 4; ++r) {
                float v = acc[mi][ni][r] + bv;
                if (out_f16)
                    ((_Float16*)Cv)[(size_t)(row + r) * N + col] = (_Float16)v;
                else
                    ((float*)Cv)[(size_t)(row + r) * N + col] = v;
            }
        }
    }
}

// ---------------- persistent recurrent kernel ----------------
// 256 WGs x 512 threads, 1 WG/CU. Wave w of WG b owns hidden unit b*8+w.
// W_hh fp16 pinned in AGPRs. Sync: tagged words hs32[t][u]=(t<<16)|f16(h).
// Consumers: 3-deep pipelined hot poll of the wave's 256-word slice, 4
// coalesced single-dword loads per slot (lane polls word j*64+lane). All
// poll registers are scalar dwords so every s_waitcnt ties them ("+v" on
// single regs is supported; round-8 fail was uint4 ties) -- checks cannot
// hoist above waits, and the post-loop vmcnt(0) drain ties all 12 regs so
// no in-flight load lands in a reassigned register (round-7 crash fix).
__global__ __launch_bounds__(512, 2) void lstm_rec_k(const _Float16* __restrict__ Whh16,
                                                     const _Float16* __restrict__ xg,
                                                     unsigned* __restrict__ hs32) {
    const int tid = threadIdx.x;
    const int wave = tid >> 6;
    const int lane = tid & 63;
    const int unit = (blockIdx.x << 3) + wave;   // hidden unit owned by this wave

    __shared__ unsigned short hbuf16[2][2048];   // f16 h_t ping-pong

    // weights: W[g][k][p] = dword p of Whh16[g*H + unit][k*256 + lane*4 ..+3]
    unsigned W[4][8][2];
#pragma unroll
    for (int g = 0; g < 4; ++g) {
        const _Float16* wr = Whh16 + ((size_t)(g * HH) + unit) * HH + (lane << 2);
#pragma unroll
        for (int k = 0; k < 8; ++k) {
            u32x2 v = *(const u32x2*)(wr + (k << 8));
            W[g][k][0] = v.x; W[g][k][1] = v.y;
        }
    }
#pragma unroll
    for (int g = 0; g < 4; ++g)
#pragma unroll
        for (int k = 0; k < 8; ++k)
            asm volatile("" : "+a"(W[g][k][0]), "+a"(W[g][k][1]));

    float creg = 0.0f;

    // wave-uniform scalar-load base for xg (dword aligned) and half-select
    const unsigned sh = (unit & 1) << 4;
    unsigned long long xbase = (unsigned long long)(uintptr_t)xg + ((unsigned)(unit << 1) & ~3u);

#define ISSUE4(x0, x1, x2, x3)                                                \
    asm volatile(                                                             \
        "global_load_dword %0, %4, off sc0 sc1\n\t"                           \
        "global_load_dword %1, %4, off offset:256 sc0 sc1\n\t"                \
        "global_load_dword %2, %4, off offset:512 sc0 sc1\n\t"                \
        "global_load_dword %3, %4, off offset:768 sc0 sc1"                    \
        : "=&v"(x0), "=&v"(x1), "=&v"(x2), "=&v"(x3) : "v"(pp))
#define WAIT8(x0, x1, x2, x3)                                                 \
    asm volatile("s_waitcnt vmcnt(8)"                                         \
                 : "+v"(x0), "+v"(x1), "+v"(x2), "+v"(x3) :: "memory")
#define CHECK4(x0, x1, x2, x3)                                                \
    __all((int)(((x0 >> 16) == tu) & ((x1 >> 16) == tu) &                     \
                ((x2 >> 16) == tu) & ((x3 >> 16) == tu)))

    for (int t = 0; t < TT; ++t) {
        const int buf = t & 1;
        const unsigned tu = (unsigned)t;
        // lane polls words {0,64,128,192}+lane of its wave's 256-word slice
        const unsigned* pp = hs32 + ((size_t)t << 11) + (wave << 8) + lane;

        // 1. issue 3-deep poll pipeline (4 coalesced dword loads per slot)
        unsigned a0, a1, a2, a3, b0, b1, b2, b3, c0, c1, c2, c3;
        ISSUE4(a0, a1, a2, a3);
        ISSUE4(b0, b1, b2, b3);
        ISSUE4(c0, c1, c2, c3);

        // 2. xg scalar loads (stall hides under poll flight)
        unsigned sd0, sd1, sd2, sd3;
        {
            unsigned long long xaddr = xbase + ((unsigned long long)t << 14);
            unsigned alo = __builtin_amdgcn_readfirstlane((unsigned)xaddr);
            unsigned ahi = __builtin_amdgcn_readfirstlane((unsigned)(xaddr >> 32));
            unsigned long long ua = ((unsigned long long)ahi << 32) | alo;
            asm volatile(
                "s_load_dword %0, %4, 0x0\n\t"
                "s_load_dword %1, %4, 0x1000\n\t"
                "s_load_dword %2, %4, 0x2000\n\t"
                "s_load_dword %3, %4, 0x3000\n\t"
                "s_waitcnt lgkmcnt(0)"
                : "=s"(sd0), "=s"(sd1), "=s"(sd2), "=s"(sd3)
                : "s"(ua));
        }
        float xv0 = (float)__builtin_bit_cast(_Float16, (unsigned short)((sd0 >> sh) & 0xffffu));
        float xv1 = (float)__builtin_bit_cast(_Float16, (unsigned short)((sd1 >> sh) & 0xffffu));
        float xv2 = (float)__builtin_bit_cast(_Float16, (unsigned short)((sd2 >> sh) & 0xffffu));
        float xv3 = (float)__builtin_bit_cast(_Float16, (unsigned short)((sd3 >> sh) & 0xffffu));

        // 3. rotating poll: wait-oldest (regs tied), check, reissue on miss
        unsigned h0, h1, h2, h3;
        for (;;) {
            WAIT8(a0, a1, a2, a3);
            if (CHECK4(a0, a1, a2, a3)) { h0 = a0; h1 = a1; h2 = a2; h3 = a3; break; }
            ISSUE4(a0, a1, a2, a3);
            WAIT8(b0, b1, b2, b3);
            if (CHECK4(b0, b1, b2, b3)) { h0 = b0; h1 = b1; h2 = b2; h3 = b3; break; }
            ISSUE4(b0, b1, b2, b3);
            WAIT8(c0, c1, c2, c3);
            if (CHECK4(c0, c1, c2, c3)) { h0 = c0; h1 = c1; h2 = c2; h3 = c3; break; }
            ISSUE4(c0, c1, c2, c3);
        }
        // 4. drain ALL in-flight polls with registers tied live
        asm volatile("s_waitcnt vmcnt(0)"
                     : "+v"(a0), "+v"(a1), "+v"(a2), "+v"(a3),
                       "+v"(b0), "+v"(b1), "+v"(b2), "+v"(b3),
                       "+v"(c0), "+v"(c1), "+v"(c2), "+v"(c3) :: "memory");

        // 5. stage own slice to LDS (4 b16 stores; unit = wave*256+j*64+lane)
        {
            unsigned short* hb = &hbuf16[buf][(wave << 8) + lane];
            hb[0]   = (unsigned short)h0;
            hb[64]  = (unsigned short)h1;
            hb[128] = (unsigned short)h2;
            hb[192] = (unsigned short)h3;
        }
        __syncthreads();

        // 6. dots over all 8 slices from LDS (packed f16 pairs)
        float g0 = 0.f, g1 = 0.f, g2 = 0.f, g3 = 0.f;
#define DOTK(kk) do {                                                         \
        u32x2 hp = *(const u32x2*)&hbuf16[buf][((kk) << 8) + (lane << 2)];    \
        f16x2 hlo = u2h(hp.x), hhi = u2h(hp.y);                               \
        g0 = FDOT2(u2h(W[0][kk][0]), hlo, g0);                                \
        g0 = FDOT2(u2h(W[0][kk][1]), hhi, g0);                                \
        g1 = FDOT2(u2h(W[1][kk][0]), hlo, g1);                                \
        g1 = FDOT2(u2h(W[1][kk][1]), hhi, g1);                                \
        g2 = FDOT2(u2h(W[2][kk][0]), hlo, g2);                                \
        g2 = FDOT2(u2h(W[2][kk][1]), hhi, g2);                                \
        g3 = FDOT2(u2h(W[3][kk][0]), hlo, g3);                                \
        g3 = FDOT2(u2h(W[3][kk][1]), hhi, g3);                                \
    } while (0)
        DOTK(0); DOTK(1); DOTK(2); DOTK(3);
        DOTK(4); DOTK(5); DOTK(6); DOTK(7);
#undef DOTK

        // 7. wave reduce (DPP ladder), uniform result
        float gi = dpp_sum64(g0) + xv0;
        float gf = dpp_sum64(g1) + xv1;
        float gg = dpp_sum64(g2) + xv2;
        float go = dpp_sum64(g3) + xv3;

        // 8. activation (uniform across lanes)
        float ei = __expf(-gi), ef = __expf(-gf), eo = __expf(-go);
        float eg = __expf(-2.0f * gg);
        float si = 1.0f / (1.0f + ei);
        float sf = 1.0f / (1.0f + ef);
        float so = 1.0f / (1.0f + eo);
        float tg = 2.0f / (1.0f + eg) - 1.0f;
        creg = sf * creg + si * tg;
        float ec = __expf(-2.0f * creg);
        float th = 2.0f / (1.0f + ec) - 1.0f;
        float h = so * th;
        _Float16 fh = (_Float16)h;
        unsigned word = ((tu + 1u) << 16) |
                        (unsigned)__builtin_bit_cast(unsigned short, fh);

        // 9. publish (fire-and-forget; retired by next step's vmcnt waits)
        if (lane == 0) {
            unsigned* hd = hs32 + (((size_t)(t + 1)) << 11) + unit;
            asm volatile("global_store_dword %0, %1, off sc0 sc1"
                         :: "v"(hd), "v"(word));
        }
    }
#undef ISSUE4
#undef WAIT8
#undef CHECK4
}

// ---------------- log-softmax over rows of [T][TAGS] ----------------
__global__ __launch_bounds__(256) void lsm_k(const float* __restrict__ tag,
                                             float* __restrict__ out) {
    const int row = blockIdx.x, tid = threadIdx.x;
    const int wave = tid >> 6, lane = tid & 63;
    const float* p = tag + ((size_t)row << 10);
    float v0 = p[tid], v1 = p[tid + 256], v2 = p[tid + 512], v3 = p[tid + 768];
    float m = fmaxf(fmaxf(v0, v1), fmaxf(v2, v3));
#pragma unroll
    for (int off = 32; off >= 1; off >>= 1) m = fmaxf(m, __shfl_xor(m, off, 64));
    __shared__ float redm[4];
    __shared__ float reds[4];
    if (lane == 0) redm[wave] = m;
    __syncthreads();
    m = fmaxf(fmaxf(redm[0], redm[1]), fmaxf(redm[2], redm[3]));
    float s = __expf(v0 - m) + __expf(v1 - m) + __expf(v2 - m) + __expf(v3 - m);
#pragma unroll
    for (int off = 32; off >= 1; off >>= 1) s += __shfl_xor(s, off, 64);
    if (lane == 0) reds[wave] = s;
    __syncthreads();
    s = reds[0] + reds[1] + reds[2] + reds[3];
    float lse = m + __logf(s);
    float* o = out + ((size_t)row << 10);
    o[tid] = v0 - lse; o[tid + 256] = v1 - lse;
    o[tid + 512] = v2 - lse; o[tid + 768] = v3 - lse;
}

extern "C" void kernel_launch(void* const* d_in, const int* in_sizes, int n_in,
                              void* d_out, int out_size, void* d_ws, size_t ws_size,
                              hipStream_t stream) {
    const float* x    = (const float*)d_in[0];
    const float* Wih  = (const float*)d_in[1];
    const float* Whh  = (const float*)d_in[2];
    const float* bih  = (const float*)d_in[3];
    const float* bhh  = (const float*)d_in[4];
    const float* Wout = (const float*)d_in[5];
    const float* bout = (const float*)d_in[6];
    float* out = (float*)d_out;

    // workspace carve with time-sliced aliasing (all uses stream-ordered):
    //  A: hs32 [16.8MB] tagged h words; aliased by `tag` in phase C
    //  B: xg   [32MB]   f16 gate preacts
    //  C: 33.6MB region:
    //     pre-GEMM-A: xbf @C+0 (4MB), wihbf @C+4MB (16MB)
    //     pre-rec   : Whh16 @C+0 (33.6MB)   [cvt AFTER phase A]
    //     post-rec  : woutbf @C+0 (4MB), hs bf16 @C+4MB (8MB)
    char* ws = (char*)d_ws;
    size_t off = 0;
    unsigned* hs32 = (unsigned*)(ws + off); off += (size_t)(TT + 1) * HH * 4;   // 16.8MB
    float* tag = (float*)hs32;                                                   // alias
    _Float16* xg = (_Float16*)(ws + off); off += (size_t)TT * G4 * 2;            // 32MB
    char* C = ws + off; off += (size_t)G4 * HH * 2;                              // 33.6MB
    unsigned short* xbf    = (unsigned short*)(C);
    unsigned short* wihbf  = (unsigned short*)(C + ((size_t)TT * DD * 2) * 2);   // C+4MB
    _Float16* Whh16        = (_Float16*)(C);
    unsigned short* woutbf = (unsigned short*)(C);
    unsigned short* hs     = (unsigned short*)(C + (size_t)4 * 1024 * 1024);     // C+4MB

    // clear ALL tags every call (h_0 = tag 0 + f16 zero; also prevents timed
    // replays from observing stale tags)
    hipMemsetAsync(hs32, 0, (size_t)(TT + 1) * HH * 4, stream);

    // converts for phase A
    cvt_bf16_k<<<(TT * DD) / 1024, 256, 0, stream>>>(x, xbf, TT * DD);
    cvt_bf16_k<<<(G4 * DD) / 1024, 256, 0, stream>>>(Wih, wihbf, G4 * DD);

    // phase A: xg[T][4H] (f16) = x @ W_ih^T + (b_ih + b_hh)
    gemm_bt_k<<<dim3(G4 / 128, TT / 128), 256, 0, stream>>>(xbf, wihbf, (void*)xg,
                                                            bih, bhh, TT, G4, DD, 1);

    // W_hh -> f16 (overwrites xbf/wihbf region — phase A is done with them)
    cvt_f16_k<<<(G4 * HH) / 1024, 256, 0, stream>>>(Whh, Whh16, G4 * HH);

    // phase B: recurrence (persistent dataflow kernel, 1 WG/CU)
    {
        const _Float16* whh_p = Whh16;
        const _Float16* xg_p = xg;
        unsigned* hs32_p = hs32;
        void* args[] = {(void*)&whh_p, (void*)&xg_p, (void*)&hs32_p};
        hipLaunchCooperativeKernel((const void*)lstm_rec_k, dim3(256), dim3(512), args, 0,
                                   stream);
    }

    // converts for phase C (overwrite Whh16 region — recurrence is done)
    cvt_bf16_k<<<(TAGS_ * HH) / 1024, 256, 0, stream>>>(Wout, woutbf, TAGS_ * HH);
    cvt_lo16f_k<<<(TT * HH) / 1024, 256, 0, stream>>>(hs32 + HH, hs, TT * HH);

    // phase C: tag[T][TAGS] = hs @ W_out^T + b_out  (tag aliases hs32; the
    // post-pass above already consumed hs32)
    gemm_bt_k<<<dim3(TAGS_ / 128, TT / 128), 256, 0, stream>>>(hs, woutbf, (void*)tag,
                                                               bout, nullptr,
                                                               TT, TAGS_, HH, 0);

    // log-softmax
    lsm_k<<<TT, 256, 0, stream>>>(tag, out);
}